// Round 6
// baseline (1226.442 us; speedup 1.0000x reference)
//
#include <hip/hip_runtime.h>
#include <cstdint>
#include <cstddef>

#define SEQ   4096
#define NB    4
#define DM    256
#define NOUT  128
#define MROWS 16384
#define EPS_LN 1e-5f
#define LDP   40   // LDS row stride in bf16 elems (32 + 8 pad, keeps 16B alignment)
#define LDA   36   // f32 LDS A-tile row stride (32 + 4, keeps 16B alignment)
#define LDW   132  // f32 LDS W-tile row stride (128 + 4, keeps 16B alignment)

typedef __attribute__((ext_vector_type(4))) float          f32x4;
typedef __attribute__((ext_vector_type(8))) unsigned short u16x8;
typedef __attribute__((ext_vector_type(4))) unsigned short u16x4;
typedef __attribute__((ext_vector_type(8))) __bf16         bf16x8;

static __device__ __forceinline__ unsigned short f2bf(float f) {
  unsigned int u = __builtin_bit_cast(unsigned int, f);
  return (unsigned short)((u + 0x7FFFu + ((u >> 16) & 1u)) >> 16);  // RNE
}
static __device__ __forceinline__ float bf2f(unsigned short s) {
  return __builtin_bit_cast(float, (unsigned int)s << 16);
}

static __device__ __forceinline__ f32x4 mfma16(u16x8 a, u16x8 b, f32x4 c) {
  return __builtin_amdgcn_mfma_f32_16x16x32_bf16(
      __builtin_bit_cast(bf16x8, a), __builtin_bit_cast(bf16x8, b), c, 0, 0, 0);
}

// stage [rows][32] bf16 tile (row-major src, elem stride `stride`) into lds[rows][LDP]
static __device__ __forceinline__ void stage_bf16(
    unsigned short* __restrict__ lds, const unsigned short* __restrict__ src,
    long row0, int stride, int kc, int rows, int tid, int nthr) {
  const int chunks = rows * 4;
  for (int c = tid; c < chunks; c += nthr) {
    int r = c >> 2, c8 = (c & 3) << 3;
    *reinterpret_cast<u16x8*>(lds + r * LDP + c8) =
        *reinterpret_cast<const u16x8*>(src + (size_t)(row0 + r) * stride + kc + c8);
  }
}

// stage [rows][32] from f32 src, converting to bf16
static __device__ __forceinline__ void stage_f32(
    unsigned short* __restrict__ lds, const float* __restrict__ src,
    long row0, int stride, int kc, int rows, int tid, int nthr) {
  const int groups = rows * 8;
  for (int g = tid; g < groups; g += nthr) {
    int r = g >> 3, c4 = (g & 7) << 2;
    f32x4 v = *reinterpret_cast<const f32x4*>(src + (size_t)(row0 + r) * stride + kc + c4);
    u16x4 o;
    o[0] = f2bf(v[0]); o[1] = f2bf(v[1]); o[2] = f2bf(v[2]); o[3] = f2bf(v[3]);
    *reinterpret_cast<u16x4*>(lds + r * LDP + c4) = o;
  }
}

// ---- fp32 staging helpers (256 threads fixed) ----
// stage [64][32] from f32 src -> f32 lds (stride LDA)
static __device__ __forceinline__ void stageA_f32(
    float* lds, const float* __restrict__ src, long row0, int stride, int kc, int tid) {
  int r = tid >> 2, c8 = (tid & 3) << 3;
  f32x4 lo = *reinterpret_cast<const f32x4*>(src + (size_t)(row0 + r) * stride + kc + c8);
  f32x4 hi = *reinterpret_cast<const f32x4*>(src + (size_t)(row0 + r) * stride + kc + c8 + 4);
  *reinterpret_cast<f32x4*>(lds + r * LDA + c8) = lo;
  *reinterpret_cast<f32x4*>(lds + r * LDA + c8 + 4) = hi;
}
// stage W rows [kc..kc+32) x 128 cols, row stride `wstride`, from col `colbase`
static __device__ __forceinline__ void stageW(
    float* lds, const float* __restrict__ W, int kc, int wstride, int colbase, int tid) {
  for (int wi = tid; wi < 1024; wi += 256) {
    int r = wi >> 5, c4 = (wi & 31) << 2;
    *reinterpret_cast<f32x4*>(lds + r * LDW + c4) =
        *reinterpret_cast<const f32x4*>(W + (size_t)(kc + r) * wstride + colbase + c4);
  }
}

// ======== qkv (fp32 exact): out = x @ W + b; epilogue per z ==========
// z=0: Qf32 + tanh(Q) bf16;  z=1: K bf16 + tanh(K) bf16;  z=2: V hi/lo transposed
__global__ __launch_bounds__(256) void qkv_f32_kernel(
    const float* __restrict__ x1, const float* __restrict__ x2,
    const float* __restrict__ Wq, const float* __restrict__ Wk, const float* __restrict__ Wv,
    const float* __restrict__ bq, const float* __restrict__ bk, const float* __restrict__ bv,
    float* __restrict__ Qf, unsigned short* __restrict__ tQh,
    unsigned short* __restrict__ Khi, unsigned short* __restrict__ tKh,
    unsigned short* __restrict__ VtHi, unsigned short* __restrict__ VtLo) {
  __shared__ float A1[64 * LDA], Wc1[32 * LDW];
  const int z = blockIdx.z;
  const float* x = (z == 0) ? x2 : x1;
  const float* W = (z == 0) ? Wq : ((z == 1) ? Wk : Wv);
  const float* bias = (z == 0) ? bq : ((z == 1) ? bk : bv);
  const long rowbase = (long)blockIdx.x * 64;
  const int colbase = blockIdx.y * 128;
  const int tid = threadIdx.x;
  const int rowp = tid >> 3, colg = tid & 7;
  const int col0 = colg * 16;

  f32x4 acc[2][4];
#pragma unroll
  for (int i = 0; i < 2; ++i)
#pragma unroll
    for (int j = 0; j < 4; ++j) acc[i][j] = f32x4{0.f, 0.f, 0.f, 0.f};

  for (int kc = 0; kc < 256; kc += 32) {
    stageA_f32(A1, x, rowbase, 256, kc, tid);
    stageW(Wc1, W, kc, 256, colbase, tid);
    __syncthreads();
    for (int kk = 0; kk < 32; ++kk) {
      float a0 = A1[(2 * rowp) * LDA + kk], a1 = A1[(2 * rowp + 1) * LDA + kk];
      const float* wr = Wc1 + kk * LDW + col0;
#pragma unroll
      for (int j = 0; j < 4; ++j) {
        f32x4 wv = *reinterpret_cast<const f32x4*>(wr + j * 4);
        acc[0][j] += a0 * wv;  acc[1][j] += a1 * wv;
      }
    }
    __syncthreads();
  }

#pragma unroll
  for (int i = 0; i < 2; ++i) {
    long row = rowbase + 2 * rowp + i;
#pragma unroll
    for (int j = 0; j < 4; ++j) {
      f32x4 bb = *reinterpret_cast<const f32x4*>(bias + colbase + col0 + j * 4);
#pragma unroll
      for (int c = 0; c < 4; ++c) {
        int col = colbase + col0 + j * 4 + c;
        float v = acc[i][j][c] + bb[c];
        size_t idx = (size_t)row * 256 + col;
        if (z == 0) {
          Qf[idx] = v;
          tQh[idx] = f2bf(tanhf(v));
        } else if (z == 1) {
          Khi[idx] = f2bf(v);
          tKh[idx] = f2bf(tanhf(v));
        } else {
          int b_ = (int)(row >> 12), ri = (int)(row & 4095);
          size_t vidx = ((size_t)b_ * 256 + col) * 4096 + ri;
          unsigned short h = f2bf(v);
          VtHi[vidx] = h;
          VtLo[vidx] = f2bf(v - bf2f(h));
        }
      }
    }
  }
}

// ---------------- score: S = QK * (tanhGEMM+1)*0.5 / 16, + per-tile m,l ------------
__global__ __launch_bounds__(512) void score_kernel(
    const float* __restrict__ Qf, const unsigned short* __restrict__ tQh,
    const unsigned short* __restrict__ Khi, const unsigned short* __restrict__ tKh,
    float* __restrict__ S, float* __restrict__ partials) {
  __shared__ unsigned short Qs[128 * LDP], tQs[128 * LDP], Ks[128 * LDP], tKs[128 * LDP];
  const int qt = blockIdx.x, kt = blockIdx.y, b = blockIdx.z;
  const int tid = threadIdx.x;
  const int w = tid >> 6, l = tid & 63, l15 = l & 15, lg = l >> 4;
  const long qrow0 = (long)b * SEQ + qt * 128;
  const long krow0 = (long)b * SEQ + kt * 128;

  f32x4 zero = {0.f, 0.f, 0.f, 0.f};
  f32x4 accS[8], accT[8];
#pragma unroll
  for (int fn = 0; fn < 8; ++fn) { accS[fn] = zero; accT[fn] = zero; }

  for (int kc = 0; kc < 256; kc += 32) {
    stage_f32(Qs, Qf, qrow0, 256, kc, 128, tid, 512);
    stage_bf16(tQs, tQh, qrow0, 256, kc, 128, tid, 512);
    stage_bf16(Ks, Khi, krow0, 256, kc, 128, tid, 512);
    stage_bf16(tKs, tKh, krow0, 256, kc, 128, tid, 512);
    __syncthreads();
    u16x8 aq = *reinterpret_cast<const u16x8*>(Qs + (w * 16 + l15) * LDP + lg * 8);
    u16x8 at = *reinterpret_cast<const u16x8*>(tQs + (w * 16 + l15) * LDP + lg * 8);
#pragma unroll
    for (int fn = 0; fn < 8; ++fn) {
      u16x8 bk_ = *reinterpret_cast<const u16x8*>(Ks + (fn * 16 + l15) * LDP + lg * 8);
      u16x8 bt_ = *reinterpret_cast<const u16x8*>(tKs + (fn * 16 + l15) * LDP + lg * 8);
      accS[fn] = mfma16(aq, bk_, accS[fn]);
      accT[fn] = mfma16(at, bt_, accT[fn]);
    }
    __syncthreads();
  }

  float sv[8][4];
#pragma unroll
  for (int fn = 0; fn < 8; ++fn)
#pragma unroll
    for (int r = 0; r < 4; ++r)
      sv[fn][r] = accS[fn][r] * (accT[fn][r] + 1.0f) * 0.5f * 0.0625f;

  // write raw scores
#pragma unroll
  for (int fn = 0; fn < 8; ++fn)
#pragma unroll
    for (int r = 0; r < 4; ++r) {
      long q = qrow0 + w * 16 + lg * 4 + r;
      S[(size_t)q * SEQ + kt * 128 + fn * 16 + l15] = sv[fn][r];
    }

  // per-row block-local max / expsum
#pragma unroll
  for (int r = 0; r < 4; ++r) {
    float m = -1e30f;
#pragma unroll
    for (int fn = 0; fn < 8; ++fn) m = fmaxf(m, sv[fn][r]);
    m = fmaxf(m, __shfl_xor(m, 1));
    m = fmaxf(m, __shfl_xor(m, 2));
    m = fmaxf(m, __shfl_xor(m, 4));
    m = fmaxf(m, __shfl_xor(m, 8));
    float ls = 0.f;
#pragma unroll
    for (int fn = 0; fn < 8; ++fn) ls += __expf(sv[fn][r] - m);
    ls += __shfl_xor(ls, 1);
    ls += __shfl_xor(ls, 2);
    ls += __shfl_xor(ls, 4);
    ls += __shfl_xor(ls, 8);
    if (l15 == 0) {
      long q = qrow0 + w * 16 + lg * 4 + r;
      partials[((size_t)q * 32 + kt) * 2 + 0] = m;
      partials[((size_t)q * 32 + kt) * 2 + 1] = ls;
    }
  }
}

// ---------------- merge split-k softmax stats -----------------
__global__ __launch_bounds__(256) void merge_kernel(const float* __restrict__ partials,
                                                    float* __restrict__ mrow,
                                                    float* __restrict__ linv) {
  int row = blockIdx.x * 256 + threadIdx.x;
  float m = -1e30f;
  for (int t = 0; t < 32; ++t) m = fmaxf(m, partials[(size_t)row * 64 + t * 2]);
  float ls = 0.f;
  for (int t = 0; t < 32; ++t)
    ls += partials[(size_t)row * 64 + t * 2 + 1] * __expf(partials[(size_t)row * 64 + t * 2] - m);
  mrow[row] = m;
  linv[row] = 1.0f / ls;
}

// ---- pv: attn = exp(S-m)/l (in place), Qh = attn @ V, split-bf16 P and V ----
__global__ __launch_bounds__(256) void pv_kernel(
    float* __restrict__ S, const float* __restrict__ mrow, const float* __restrict__ linv,
    const unsigned short* __restrict__ VtHi, const unsigned short* __restrict__ VtLo,
    float* __restrict__ Qhf) {
  __shared__ unsigned short VsH[256 * LDP], VsL[256 * LDP];
  const int qt = blockIdx.x, b = blockIdx.y;
  const int tid = threadIdx.x;
  const int w = tid >> 6, l = tid & 63, l15 = l & 15, lg = l >> 4;
  const long qrow_a = (long)b * SEQ + qt * 64 + w * 16 + l15;  // this lane's A row
  const float m_a = mrow[qrow_a];
  const float li_a = linv[qrow_a];
  const unsigned short* VtHb = VtHi + (size_t)b * 256 * 4096;
  const unsigned short* VtLb = VtLo + (size_t)b * 256 * 4096;

  f32x4 zero = {0.f, 0.f, 0.f, 0.f};
  f32x4 acc[16];
#pragma unroll
  for (int fn = 0; fn < 16; ++fn) acc[fn] = zero;

  for (int kc = 0; kc < SEQ; kc += 32) {
    for (int c = tid; c < 1024; c += 256) {
      int d = c >> 2, c8 = (c & 3) << 3;
      *reinterpret_cast<u16x8*>(VsH + d * LDP + c8) =
          *reinterpret_cast<const u16x8*>(VtHb + (size_t)d * 4096 + kc + c8);
      *reinterpret_cast<u16x8*>(VsL + d * LDP + c8) =
          *reinterpret_cast<const u16x8*>(VtLb + (size_t)d * 4096 + kc + c8);
    }
    __syncthreads();

    float* Srow = S + (size_t)qrow_a * SEQ + kc + lg * 8;
    f32x4 s0 = *reinterpret_cast<const f32x4*>(Srow);
    f32x4 s1 = *reinterpret_cast<const f32x4*>(Srow + 4);
    f32x4 p0, p1;
#pragma unroll
    for (int j = 0; j < 4; ++j) p0[j] = __expf(s0[j] - m_a) * li_a;
#pragma unroll
    for (int j = 0; j < 4; ++j) p1[j] = __expf(s1[j] - m_a) * li_a;
    *reinterpret_cast<f32x4*>(Srow) = p0;
    *reinterpret_cast<f32x4*>(Srow + 4) = p1;
    u16x8 aH, aL;
#pragma unroll
    for (int j = 0; j < 4; ++j) {
      aH[j] = f2bf(p0[j]);     aL[j] = f2bf(p0[j] - bf2f(aH[j]));
      aH[4 + j] = f2bf(p1[j]); aL[4 + j] = f2bf(p1[j] - bf2f(aH[4 + j]));
    }

#pragma unroll
    for (int fn = 0; fn < 16; ++fn) {
      u16x8 vH = *reinterpret_cast<const u16x8*>(VsH + (fn * 16 + l15) * LDP + lg * 8);
      u16x8 vL = *reinterpret_cast<const u16x8*>(VsL + (fn * 16 + l15) * LDP + lg * 8);
      acc[fn] = mfma16(aH, vH, acc[fn]);
      acc[fn] = mfma16(aL, vH, acc[fn]);
      acc[fn] = mfma16(aH, vL, acc[fn]);
    }
    __syncthreads();
  }

  long q0 = (long)b * SEQ + qt * 64 + w * 16;
#pragma unroll
  for (int fn = 0; fn < 16; ++fn)
#pragma unroll
    for (int r = 0; r < 4; ++r) {
      long q = q0 + lg * 4 + r;
      Qhf[(size_t)q * 256 + fn * 16 + l15] = acc[fn][r];
    }
}

// =========================  fp32 gate head  =========================
// Per block: 64 rows x 128 cols. 256 threads: rowp = tid>>3 (2 rows each),
// colg = tid&7 (16 cols each). LN reduction over colg via shfl_xor 1,2,4.

// ---- gate G = LN(relu(relu(Q W1+b1)+relu(Qh W2+b2))), fp32 ----
__global__ __launch_bounds__(256) void gateG_f32_kernel(
    const float* __restrict__ Qf, const float* __restrict__ Qhf,
    const float* __restrict__ W1, const float* __restrict__ W2,
    const float* __restrict__ b1, const float* __restrict__ b2,
    const float* __restrict__ ggam, const float* __restrict__ gbet,
    float* __restrict__ G) {
  __shared__ float A1[64 * LDA], A2[64 * LDA], Wc1[32 * LDW], Wc2[32 * LDW];
  const long rowbase = (long)blockIdx.x * 64;
  const int tid = threadIdx.x;
  const int rowp = tid >> 3, colg = tid & 7;
  const int col0 = colg * 16;

  f32x4 acc1[2][4], acc2[2][4];
#pragma unroll
  for (int i = 0; i < 2; ++i)
#pragma unroll
    for (int j = 0; j < 4; ++j) {
      acc1[i][j] = f32x4{0.f, 0.f, 0.f, 0.f};
      acc2[i][j] = f32x4{0.f, 0.f, 0.f, 0.f};
    }

  for (int kc = 0; kc < 256; kc += 32) {
    stageA_f32(A1, Qf, rowbase, 256, kc, tid);
    stageA_f32(A2, Qhf, rowbase, 256, kc, tid);
    stageW(Wc1, W1, kc, 128, 0, tid);
    stageW(Wc2, W2, kc, 128, 0, tid);
    __syncthreads();
    for (int kk = 0; kk < 32; ++kk) {
      float a10 = A1[(2 * rowp) * LDA + kk], a11 = A1[(2 * rowp + 1) * LDA + kk];
      float a20 = A2[(2 * rowp) * LDA + kk], a21 = A2[(2 * rowp + 1) * LDA + kk];
      const float* w1r = Wc1 + kk * LDW + col0;
      const float* w2r = Wc2 + kk * LDW + col0;
#pragma unroll
      for (int j = 0; j < 4; ++j) {
        f32x4 w1v = *reinterpret_cast<const f32x4*>(w1r + j * 4);
        f32x4 w2v = *reinterpret_cast<const f32x4*>(w2r + j * 4);
        acc1[0][j] += a10 * w1v;  acc1[1][j] += a11 * w1v;
        acc2[0][j] += a20 * w2v;  acc2[1][j] += a21 * w2v;
      }
    }
    __syncthreads();
  }

  float u[2][16];
#pragma unroll
  for (int j = 0; j < 4; ++j) {
    f32x4 bb1 = *reinterpret_cast<const f32x4*>(b1 + col0 + j * 4);
    f32x4 bb2 = *reinterpret_cast<const f32x4*>(b2 + col0 + j * 4);
#pragma unroll
    for (int i = 0; i < 2; ++i)
#pragma unroll
      for (int c = 0; c < 4; ++c) {
        float v = fmaxf(acc1[i][j][c] + bb1[c], 0.f) + fmaxf(acc2[i][j][c] + bb2[c], 0.f);
        u[i][j * 4 + c] = fmaxf(v, 0.f);
      }
  }
#pragma unroll
  for (int i = 0; i < 2; ++i) {
    float s = 0.f, ss = 0.f;
#pragma unroll
    for (int c = 0; c < 16; ++c) { s += u[i][c]; ss += u[i][c] * u[i][c]; }
    s += __shfl_xor(s, 1); ss += __shfl_xor(ss, 1);
    s += __shfl_xor(s, 2); ss += __shfl_xor(ss, 2);
    s += __shfl_xor(s, 4); ss += __shfl_xor(ss, 4);
    float mean = s * (1.f / 128.f);
    float var = ss * (1.f / 128.f) - mean * mean;
    float rs = rsqrtf(fmaxf(var, 0.f) + EPS_LN);
    long row = rowbase + 2 * rowp + i;
#pragma unroll
    for (int j = 0; j < 4; ++j) {
      f32x4 gg = *reinterpret_cast<const f32x4*>(ggam + col0 + j * 4);
      f32x4 gb = *reinterpret_cast<const f32x4*>(gbet + col0 + j * 4);
      f32x4 o;
#pragma unroll
      for (int c = 0; c < 4; ++c)
        o[c] = (u[i][j * 4 + c] - mean) * rs * gg[c] + gb[c];
      *reinterpret_cast<f32x4*>(G + (size_t)row * 128 + col0 + j * 4) = o;
    }
  }
}

// ---- gate E + product (in place): G *= LN(relu(Qh W3+b3)), fp32 ----
__global__ __launch_bounds__(256) void gateE_f32_kernel(
    const float* __restrict__ Qhf, const float* __restrict__ W3,
    const float* __restrict__ b3, const float* __restrict__ egam,
    const float* __restrict__ ebet, float* G) {
  __shared__ float A1[64 * LDA], Wc1[32 * LDW];
  const long rowbase = (long)blockIdx.x * 64;
  const int tid = threadIdx.x;
  const int rowp = tid >> 3, colg = tid & 7;
  const int col0 = colg * 16;

  f32x4 acc[2][4];
#pragma unroll
  for (int i = 0; i < 2; ++i)
#pragma unroll
    for (int j = 0; j < 4; ++j) acc[i][j] = f32x4{0.f, 0.f, 0.f, 0.f};

  for (int kc = 0; kc < 256; kc += 32) {
    stageA_f32(A1, Qhf, rowbase, 256, kc, tid);
    stageW(Wc1, W3, kc, 128, 0, tid);
    __syncthreads();
    for (int kk = 0; kk < 32; ++kk) {
      float a0 = A1[(2 * rowp) * LDA + kk], a1 = A1[(2 * rowp + 1) * LDA + kk];
      const float* wr = Wc1 + kk * LDW + col0;
#pragma unroll
      for (int j = 0; j < 4; ++j) {
        f32x4 wv = *reinterpret_cast<const f32x4*>(wr + j * 4);
        acc[0][j] += a0 * wv;  acc[1][j] += a1 * wv;
      }
    }
    __syncthreads();
  }

  float u[2][16];
#pragma unroll
  for (int j = 0; j < 4; ++j) {
    f32x4 bb = *reinterpret_cast<const f32x4*>(b3 + col0 + j * 4);
#pragma unroll
    for (int i = 0; i < 2; ++i)
#pragma unroll
      for (int c = 0; c < 4; ++c)
        u[i][j * 4 + c] = fmaxf(acc[i][j][c] + bb[c], 0.f);
  }
#pragma unroll
  for (int i = 0; i < 2; ++i) {
    float s = 0.f, ss = 0.f;
#pragma unroll
    for (int c = 0; c < 16; ++c) { s += u[i][c]; ss += u[i][c] * u[i][c]; }
    s += __shfl_xor(s, 1); ss += __shfl_xor(ss, 1);
    s += __shfl_xor(s, 2); ss += __shfl_xor(ss, 2);
    s += __shfl_xor(s, 4); ss += __shfl_xor(ss, 4);
    float mean = s * (1.f / 128.f);
    float var = ss * (1.f / 128.f) - mean * mean;
    float rs = rsqrtf(fmaxf(var, 0.f) + EPS_LN);
    long row = rowbase + 2 * rowp + i;
#pragma unroll
    for (int j = 0; j < 4; ++j) {
      f32x4 eg = *reinterpret_cast<const f32x4*>(egam + col0 + j * 4);
      f32x4 eb = *reinterpret_cast<const f32x4*>(ebet + col0 + j * 4);
      f32x4 gv = *reinterpret_cast<f32x4*>(G + (size_t)row * 128 + col0 + j * 4);
      f32x4 o;
#pragma unroll
      for (int c = 0; c < 4; ++c) {
        float e = (u[i][j * 4 + c] - mean) * rs * eg[c] + eb[c];
        o[c] = gv[c] * e;
      }
      *reinterpret_cast<f32x4*>(G + (size_t)row * 128 + col0 + j * 4) = o;  // GE in place
    }
  }
}

// ---- out0 = relu(Q Wf + bf) + relu(GE Wc + bc), fp32 ----
__global__ __launch_bounds__(256) void outc_f32_kernel(
    const float* __restrict__ Qf, const float* __restrict__ GE,
    const float* __restrict__ Wf, const float* __restrict__ Wcw,
    const float* __restrict__ bf_, const float* __restrict__ bc_,
    float* __restrict__ out0) {
  __shared__ float A1[64 * LDA], Wc1[32 * LDW];
  const long rowbase = (long)blockIdx.x * 64;
  const int tid = threadIdx.x;
  const int rowp = tid >> 3, colg = tid & 7;
  const int col0 = colg * 16;

  f32x4 acc4[2][4], acc5[2][4];
#pragma unroll
  for (int i = 0; i < 2; ++i)
#pragma unroll
    for (int j = 0; j < 4; ++j) {
      acc4[i][j] = f32x4{0.f, 0.f, 0.f, 0.f};
      acc5[i][j] = f32x4{0.f, 0.f, 0.f, 0.f};
    }

  for (int kc = 0; kc < 256; kc += 32) {
    stageA_f32(A1, Qf, rowbase, 256, kc, tid);
    stageW(Wc1, Wf, kc, 128, 0, tid);
    __syncthreads();
    for (int kk = 0; kk < 32; ++kk) {
      float a0 = A1[(2 * rowp) * LDA + kk], a1 = A1[(2 * rowp + 1) * LDA + kk];
      const float* wr = Wc1 + kk * LDW + col0;
#pragma unroll
      for (int j = 0; j < 4; ++j) {
        f32x4 wv = *reinterpret_cast<const f32x4*>(wr + j * 4);
        acc4[0][j] += a0 * wv;  acc4[1][j] += a1 * wv;
      }
    }
    __syncthreads();
  }
  for (int kc = 0; kc < 128; kc += 32) {
    stageA_f32(A1, GE, rowbase, 128, kc, tid);
    stageW(Wc1, Wcw, kc, 128, 0, tid);
    __syncthreads();
    for (int kk = 0; kk < 32; ++kk) {
      float a0 = A1[(2 * rowp) * LDA + kk], a1 = A1[(2 * rowp + 1) * LDA + kk];
      const float* wr = Wc1 + kk * LDW + col0;
#pragma unroll
      for (int j = 0; j < 4; ++j) {
        f32x4 wv = *reinterpret_cast<const f32x4*>(wr + j * 4);
        acc5[0][j] += a0 * wv;  acc5[1][j] += a1 * wv;
      }
    }
    __syncthreads();
  }

#pragma unroll
  for (int i = 0; i < 2; ++i) {
    long row = rowbase + 2 * rowp + i;
#pragma unroll
    for (int j = 0; j < 4; ++j) {
      f32x4 fb = *reinterpret_cast<const f32x4*>(bf_ + col0 + j * 4);
      f32x4 cb = *reinterpret_cast<const f32x4*>(bc_ + col0 + j * 4);
      f32x4 o;
#pragma unroll
      for (int c = 0; c < 4; ++c)
        o[c] = fmaxf(acc4[i][j][c] + fb[c], 0.f) + fmaxf(acc5[i][j][c] + cb[c], 0.f);
      *reinterpret_cast<f32x4*>(out0 + (size_t)row * 128 + col0 + j * 4) = o;
    }
  }
}

// ------------------------------- host launcher -------------------------------------
extern "C" void kernel_launch(void* const* d_in, const int* in_sizes, int n_in,
                              void* d_out, int out_size, void* d_ws, size_t ws_size,
                              hipStream_t stream) {
  const float* x1 = (const float*)d_in[0];
  const float* x2 = (const float*)d_in[1];
  const float* W_q = (const float*)d_in[2];  const float* b_q = (const float*)d_in[3];
  const float* W_k = (const float*)d_in[4];  const float* b_k = (const float*)d_in[5];
  const float* W_v = (const float*)d_in[6];  const float* b_v = (const float*)d_in[7];
  const float* W1  = (const float*)d_in[8];  const float* b1  = (const float*)d_in[9];
  const float* W2  = (const float*)d_in[10]; const float* b2  = (const float*)d_in[11];
  const float* W3  = (const float*)d_in[12]; const float* b3  = (const float*)d_in[13];
  const float* ggam = (const float*)d_in[14]; const float* gbet = (const float*)d_in[15];
  const float* egam = (const float*)d_in[16]; const float* ebet = (const float*)d_in[17];
  const float* W_c = (const float*)d_in[18]; const float* b_c = (const float*)d_in[19];
  const float* W_f = (const float*)d_in[20]; const float* b_f = (const float*)d_in[21];

  float* out0 = (float*)d_out;
  float* Smat = out0 + (size_t)MROWS * NOUT;  // attn region, also scratch for raw scores

  // workspace layout (bytes); peak live = 63.0 MB (< 64.8 MB proven safe in R3/R5)
  char* ws = (char*)d_ws;
  float*          Qf   = (float*)(ws + 0);               // 16 MB f32, [qkv..outc]
  unsigned short* tQh  = (unsigned short*)(ws + 16777216); // 8 MB [qkv..score]
  unsigned short* Khi  = (unsigned short*)(ws + 25165824); // 8 MB [qkv..score]
  unsigned short* tKh  = (unsigned short*)(ws + 33554432); // 8 MB [qkv..score]
  unsigned short* VtHi = (unsigned short*)(ws + 41943040); // 8 MB [qkv..pv]
  unsigned short* VtLo = (unsigned short*)(ws + 50331648); // 8 MB [qkv..pv]
  float*          part = (float*)(ws + 58720256);          // 4 MB [score..merge]
  float*          mrow = (float*)(ws + 62914560);          // 64 KB
  float*          linv = (float*)(ws + 62980096);          // 64 KB
  // overlays (regions dead after score):
  float*          Qhf  = (float*)(ws + 16777216);          // 16 MB f32 over tQh+Khi [pv..outc]
  float*          Gm   = (float*)(ws + 33554432);          // 8 MB f32 over tKh [gateG..outc]

  qkv_f32_kernel<<<dim3(256, 2, 3), 256, 0, stream>>>(
      x1, x2, W_q, W_k, W_v, b_q, b_k, b_v, Qf, tQh, Khi, tKh, VtHi, VtLo);
  score_kernel<<<dim3(32, 32, 4), 512, 0, stream>>>(Qf, tQh, Khi, tKh, Smat, part);
  merge_kernel<<<64, 256, 0, stream>>>(part, mrow, linv);
  pv_kernel<<<dim3(64, 4), 256, 0, stream>>>(Smat, mrow, linv, VtHi, VtLo, Qhf);
  gateG_f32_kernel<<<256, 256, 0, stream>>>(Qf, Qhf, W1, W2, b1, b2, ggam, gbet, Gm);
  gateE_f32_kernel<<<256, 256, 0, stream>>>(Qhf, W3, b3, egam, ebet, Gm);
  outc_f32_kernel<<<256, 256, 0, stream>>>(Qf, Gm, W_f, W_c, b_f, b_c, out0);
}

// Round 7
// 1113.776 us; speedup vs baseline: 1.1012x; 1.1012x over previous
//
#include <hip/hip_runtime.h>
#include <cstdint>
#include <cstddef>

#define SEQ   4096
#define NB    4
#define DM    256
#define NOUT  128
#define MROWS 16384
#define EPS_LN 1e-5f
#define LDP   40   // LDS row stride in bf16 elems (32 + 8 pad, keeps 16B alignment)
#define LDA   36   // f32 LDS A-tile row stride (32 + 4, keeps 16B alignment)
#define LDW   132  // f32 LDS W-tile row stride (128 + 4, keeps 16B alignment)

typedef __attribute__((ext_vector_type(4))) float          f32x4;
typedef __attribute__((ext_vector_type(8))) unsigned short u16x8;
typedef __attribute__((ext_vector_type(4))) unsigned short u16x4;
typedef __attribute__((ext_vector_type(8))) __bf16         bf16x8;

static __device__ __forceinline__ unsigned short f2bf(float f) {
  unsigned int u = __builtin_bit_cast(unsigned int, f);
  return (unsigned short)((u + 0x7FFFu + ((u >> 16) & 1u)) >> 16);  // RNE
}
static __device__ __forceinline__ float bf2f(unsigned short s) {
  return __builtin_bit_cast(float, (unsigned int)s << 16);
}

static __device__ __forceinline__ f32x4 mfma16(u16x8 a, u16x8 b, f32x4 c) {
  return __builtin_amdgcn_mfma_f32_16x16x32_bf16(
      __builtin_bit_cast(bf16x8, a), __builtin_bit_cast(bf16x8, b), c, 0, 0, 0);
}

// stage [rows][32] bf16 tile (row-major src, elem stride `stride`) into lds[rows][LDP]
static __device__ __forceinline__ void stage_bf16(
    unsigned short* __restrict__ lds, const unsigned short* __restrict__ src,
    long row0, int stride, int kc, int rows, int tid, int nthr) {
  const int chunks = rows * 4;
  for (int c = tid; c < chunks; c += nthr) {
    int r = c >> 2, c8 = (c & 3) << 3;
    *reinterpret_cast<u16x8*>(lds + r * LDP + c8) =
        *reinterpret_cast<const u16x8*>(src + (size_t)(row0 + r) * stride + kc + c8);
  }
}

// stage [rows][32] from f32 src, converting to bf16
static __device__ __forceinline__ void stage_f32(
    unsigned short* __restrict__ lds, const float* __restrict__ src,
    long row0, int stride, int kc, int rows, int tid, int nthr) {
  const int groups = rows * 8;
  for (int g = tid; g < groups; g += nthr) {
    int r = g >> 3, c4 = (g & 7) << 2;
    f32x4 v = *reinterpret_cast<const f32x4*>(src + (size_t)(row0 + r) * stride + kc + c4);
    u16x4 o;
    o[0] = f2bf(v[0]); o[1] = f2bf(v[1]); o[2] = f2bf(v[2]); o[3] = f2bf(v[3]);
    *reinterpret_cast<u16x4*>(lds + r * LDP + c4) = o;
  }
}

// ---- fp32 staging helpers (256 threads fixed) ----
// stage [64][32] from f32 src -> f32 lds (stride LDA)
static __device__ __forceinline__ void stageA_f32(
    float* lds, const float* __restrict__ src, long row0, int stride, int kc, int tid) {
  int r = tid >> 2, c8 = (tid & 3) << 3;
  f32x4 lo = *reinterpret_cast<const f32x4*>(src + (size_t)(row0 + r) * stride + kc + c8);
  f32x4 hi = *reinterpret_cast<const f32x4*>(src + (size_t)(row0 + r) * stride + kc + c8 + 4);
  *reinterpret_cast<f32x4*>(lds + r * LDA + c8) = lo;
  *reinterpret_cast<f32x4*>(lds + r * LDA + c8 + 4) = hi;
}
// stage W rows [kc..kc+32) x 128 cols, row stride `wstride`, from col `colbase`
static __device__ __forceinline__ void stageW(
    float* lds, const float* __restrict__ W, int kc, int wstride, int colbase, int tid) {
  for (int wi = tid; wi < 1024; wi += 256) {
    int r = wi >> 5, c4 = (wi & 31) << 2;
    *reinterpret_cast<f32x4*>(lds + r * LDW + c4) =
        *reinterpret_cast<const f32x4*>(W + (size_t)(kc + r) * wstride + colbase + c4);
  }
}

// -------- zero-init f32 buffer (float4 granularity) --------
__global__ __launch_bounds__(256) void zero_kernel(float* __restrict__ p, int n4) {
  int i = blockIdx.x * 256 + threadIdx.x;
  if (i < n4) reinterpret_cast<f32x4*>(p)[i] = f32x4{0.f, 0.f, 0.f, 0.f};
}

// ======== qkv (fp32 exact): out = x @ W + b; epilogue per z ==========
// z=0: Qf32 + tanh(Q) bf16;  z=1: K bf16 + tanh(K) bf16;  z=2: V hi/lo transposed
__global__ __launch_bounds__(256) void qkv_f32_kernel(
    const float* __restrict__ x1, const float* __restrict__ x2,
    const float* __restrict__ Wq, const float* __restrict__ Wk, const float* __restrict__ Wv,
    const float* __restrict__ bq, const float* __restrict__ bk, const float* __restrict__ bv,
    float* __restrict__ Qf, unsigned short* __restrict__ tQh,
    unsigned short* __restrict__ Khi, unsigned short* __restrict__ tKh,
    unsigned short* __restrict__ VtHi, unsigned short* __restrict__ VtLo) {
  __shared__ float A1[64 * LDA], Wc1[32 * LDW];
  const int z = blockIdx.z;
  const float* x = (z == 0) ? x2 : x1;
  const float* W = (z == 0) ? Wq : ((z == 1) ? Wk : Wv);
  const float* bias = (z == 0) ? bq : ((z == 1) ? bk : bv);
  const long rowbase = (long)blockIdx.x * 64;
  const int colbase = blockIdx.y * 128;
  const int tid = threadIdx.x;
  const int rowp = tid >> 3, colg = tid & 7;
  const int col0 = colg * 16;

  f32x4 acc[2][4];
#pragma unroll
  for (int i = 0; i < 2; ++i)
#pragma unroll
    for (int j = 0; j < 4; ++j) acc[i][j] = f32x4{0.f, 0.f, 0.f, 0.f};

  for (int kc = 0; kc < 256; kc += 32) {
    stageA_f32(A1, x, rowbase, 256, kc, tid);
    stageW(Wc1, W, kc, 256, colbase, tid);
    __syncthreads();
    for (int kk = 0; kk < 32; ++kk) {
      float a0 = A1[(2 * rowp) * LDA + kk], a1 = A1[(2 * rowp + 1) * LDA + kk];
      const float* wr = Wc1 + kk * LDW + col0;
#pragma unroll
      for (int j = 0; j < 4; ++j) {
        f32x4 wv = *reinterpret_cast<const f32x4*>(wr + j * 4);
        acc[0][j] += a0 * wv;  acc[1][j] += a1 * wv;
      }
    }
    __syncthreads();
  }

#pragma unroll
  for (int i = 0; i < 2; ++i) {
    long row = rowbase + 2 * rowp + i;
#pragma unroll
    for (int j = 0; j < 4; ++j) {
      f32x4 bb = *reinterpret_cast<const f32x4*>(bias + colbase + col0 + j * 4);
#pragma unroll
      for (int c = 0; c < 4; ++c) {
        int col = colbase + col0 + j * 4 + c;
        float v = acc[i][j][c] + bb[c];
        size_t idx = (size_t)row * 256 + col;
        if (z == 0) {
          Qf[idx] = v;
          tQh[idx] = f2bf(tanhf(v));
        } else if (z == 1) {
          Khi[idx] = f2bf(v);
          tKh[idx] = f2bf(tanhf(v));
        } else {
          int b_ = (int)(row >> 12), ri = (int)(row & 4095);
          size_t vidx = ((size_t)b_ * 256 + col) * 4096 + ri;
          unsigned short h = f2bf(v);
          VtHi[vidx] = h;
          VtLo[vidx] = f2bf(v - bf2f(h));
        }
      }
    }
  }
}

// ---------------- score: S = QK * (tanhGEMM+1)*0.5 / 16, + per-tile m,l ------------
__global__ __launch_bounds__(512) void score_kernel(
    const float* __restrict__ Qf, const unsigned short* __restrict__ tQh,
    const unsigned short* __restrict__ Khi, const unsigned short* __restrict__ tKh,
    float* __restrict__ S, float* __restrict__ partials) {
  __shared__ unsigned short Qs[128 * LDP], tQs[128 * LDP], Ks[128 * LDP], tKs[128 * LDP];
  const int qt = blockIdx.x, kt = blockIdx.y, b = blockIdx.z;
  const int tid = threadIdx.x;
  const int w = tid >> 6, l = tid & 63, l15 = l & 15, lg = l >> 4;
  const long qrow0 = (long)b * SEQ + qt * 128;
  const long krow0 = (long)b * SEQ + kt * 128;

  f32x4 zero = {0.f, 0.f, 0.f, 0.f};
  f32x4 accS[8], accT[8];
#pragma unroll
  for (int fn = 0; fn < 8; ++fn) { accS[fn] = zero; accT[fn] = zero; }

  for (int kc = 0; kc < 256; kc += 32) {
    stage_f32(Qs, Qf, qrow0, 256, kc, 128, tid, 512);
    stage_bf16(tQs, tQh, qrow0, 256, kc, 128, tid, 512);
    stage_bf16(Ks, Khi, krow0, 256, kc, 128, tid, 512);
    stage_bf16(tKs, tKh, krow0, 256, kc, 128, tid, 512);
    __syncthreads();
    u16x8 aq = *reinterpret_cast<const u16x8*>(Qs + (w * 16 + l15) * LDP + lg * 8);
    u16x8 at = *reinterpret_cast<const u16x8*>(tQs + (w * 16 + l15) * LDP + lg * 8);
#pragma unroll
    for (int fn = 0; fn < 8; ++fn) {
      u16x8 bk_ = *reinterpret_cast<const u16x8*>(Ks + (fn * 16 + l15) * LDP + lg * 8);
      u16x8 bt_ = *reinterpret_cast<const u16x8*>(tKs + (fn * 16 + l15) * LDP + lg * 8);
      accS[fn] = mfma16(aq, bk_, accS[fn]);
      accT[fn] = mfma16(at, bt_, accT[fn]);
    }
    __syncthreads();
  }

  float sv[8][4];
#pragma unroll
  for (int fn = 0; fn < 8; ++fn)
#pragma unroll
    for (int r = 0; r < 4; ++r)
      sv[fn][r] = accS[fn][r] * (accT[fn][r] + 1.0f) * 0.5f * 0.0625f;

  // write raw scores
#pragma unroll
  for (int fn = 0; fn < 8; ++fn)
#pragma unroll
    for (int r = 0; r < 4; ++r) {
      long q = qrow0 + w * 16 + lg * 4 + r;
      S[(size_t)q * SEQ + kt * 128 + fn * 16 + l15] = sv[fn][r];
    }

  // per-row block-local max / expsum
#pragma unroll
  for (int r = 0; r < 4; ++r) {
    float m = -1e30f;
#pragma unroll
    for (int fn = 0; fn < 8; ++fn) m = fmaxf(m, sv[fn][r]);
    m = fmaxf(m, __shfl_xor(m, 1));
    m = fmaxf(m, __shfl_xor(m, 2));
    m = fmaxf(m, __shfl_xor(m, 4));
    m = fmaxf(m, __shfl_xor(m, 8));
    float ls = 0.f;
#pragma unroll
    for (int fn = 0; fn < 8; ++fn) ls += __expf(sv[fn][r] - m);
    ls += __shfl_xor(ls, 1);
    ls += __shfl_xor(ls, 2);
    ls += __shfl_xor(ls, 4);
    ls += __shfl_xor(ls, 8);
    if (l15 == 0) {
      long q = qrow0 + w * 16 + lg * 4 + r;
      partials[((size_t)q * 32 + kt) * 2 + 0] = m;
      partials[((size_t)q * 32 + kt) * 2 + 1] = ls;
    }
  }
}

// ---------------- merge split-k softmax stats -----------------
__global__ __launch_bounds__(256) void merge_kernel(const float* __restrict__ partials,
                                                    float* __restrict__ mrow,
                                                    float* __restrict__ linv) {
  int row = blockIdx.x * 256 + threadIdx.x;
  float m = -1e30f;
  for (int t = 0; t < 32; ++t) m = fmaxf(m, partials[(size_t)row * 64 + t * 2]);
  float ls = 0.f;
  for (int t = 0; t < 32; ++t)
    ls += partials[(size_t)row * 64 + t * 2 + 1] * __expf(partials[(size_t)row * 64 + t * 2] - m);
  mrow[row] = m;
  linv[row] = 1.0f / ls;
}

// ---- pv (split-K over blockIdx.z): attn = exp(S-m)/l in place for this K-range,
//      partial Qh accumulated via atomicAdd. Split-bf16 P and V for accuracy. ----
#define PV_SPLIT 4
#define PV_KLEN  (SEQ / PV_SPLIT)   // 1024
__global__ __launch_bounds__(256) void pv_kernel(
    float* __restrict__ S, const float* __restrict__ mrow, const float* __restrict__ linv,
    const unsigned short* __restrict__ VtHi, const unsigned short* __restrict__ VtLo,
    float* __restrict__ Qhf) {
  __shared__ unsigned short VsH[256 * LDP], VsL[256 * LDP];
  const int qt = blockIdx.x, b = blockIdx.y, zs = blockIdx.z;
  const int tid = threadIdx.x;
  const int w = tid >> 6, l = tid & 63, l15 = l & 15, lg = l >> 4;
  const long qrow_a = (long)b * SEQ + qt * 64 + w * 16 + l15;  // this lane's A row
  const float m_a = mrow[qrow_a];
  const float li_a = linv[qrow_a];
  const unsigned short* VtHb = VtHi + (size_t)b * 256 * 4096;
  const unsigned short* VtLb = VtLo + (size_t)b * 256 * 4096;

  f32x4 zero = {0.f, 0.f, 0.f, 0.f};
  f32x4 acc[16];
#pragma unroll
  for (int fn = 0; fn < 16; ++fn) acc[fn] = zero;

  const int kc0 = zs * PV_KLEN;
  for (int kc = kc0; kc < kc0 + PV_KLEN; kc += 32) {
    for (int c = tid; c < 1024; c += 256) {
      int d = c >> 2, c8 = (c & 3) << 3;
      *reinterpret_cast<u16x8*>(VsH + d * LDP + c8) =
          *reinterpret_cast<const u16x8*>(VtHb + (size_t)d * 4096 + kc + c8);
      *reinterpret_cast<u16x8*>(VsL + d * LDP + c8) =
          *reinterpret_cast<const u16x8*>(VtLb + (size_t)d * 4096 + kc + c8);
    }
    __syncthreads();

    float* Srow = S + (size_t)qrow_a * SEQ + kc + lg * 8;
    f32x4 s0 = *reinterpret_cast<const f32x4*>(Srow);
    f32x4 s1 = *reinterpret_cast<const f32x4*>(Srow + 4);
    f32x4 p0, p1;
#pragma unroll
    for (int j = 0; j < 4; ++j) p0[j] = __expf(s0[j] - m_a) * li_a;
#pragma unroll
    for (int j = 0; j < 4; ++j) p1[j] = __expf(s1[j] - m_a) * li_a;
    *reinterpret_cast<f32x4*>(Srow) = p0;
    *reinterpret_cast<f32x4*>(Srow + 4) = p1;
    u16x8 aH, aL;
#pragma unroll
    for (int j = 0; j < 4; ++j) {
      aH[j] = f2bf(p0[j]);     aL[j] = f2bf(p0[j] - bf2f(aH[j]));
      aH[4 + j] = f2bf(p1[j]); aL[4 + j] = f2bf(p1[j] - bf2f(aH[4 + j]));
    }

#pragma unroll
    for (int fn = 0; fn < 16; ++fn) {
      u16x8 vH = *reinterpret_cast<const u16x8*>(VsH + (fn * 16 + l15) * LDP + lg * 8);
      u16x8 vL = *reinterpret_cast<const u16x8*>(VsL + (fn * 16 + l15) * LDP + lg * 8);
      acc[fn] = mfma16(aH, vH, acc[fn]);
      acc[fn] = mfma16(aL, vH, acc[fn]);
      acc[fn] = mfma16(aH, vL, acc[fn]);
    }
    __syncthreads();
  }

  long q0 = (long)b * SEQ + qt * 64 + w * 16;
#pragma unroll
  for (int fn = 0; fn < 16; ++fn)
#pragma unroll
    for (int r = 0; r < 4; ++r) {
      long q = q0 + lg * 4 + r;
      atomicAdd(&Qhf[(size_t)q * 256 + fn * 16 + l15], acc[fn][r]);
    }
}

// =========================  fp32 gate head  =========================
// Per block: 64 rows x 128 cols. 256 threads: rowp = tid>>3 (2 rows each),
// colg = tid&7 (16 cols each). LN reduction over colg via shfl_xor 1,2,4.

// ---- gate G = LN(relu(relu(Q W1+b1)+relu(Qh W2+b2))), fp32 ----
__global__ __launch_bounds__(256) void gateG_f32_kernel(
    const float* __restrict__ Qf, const float* __restrict__ Qhf,
    const float* __restrict__ W1, const float* __restrict__ W2,
    const float* __restrict__ b1, const float* __restrict__ b2,
    const float* __restrict__ ggam, const float* __restrict__ gbet,
    float* __restrict__ G) {
  __shared__ float A1[64 * LDA], A2[64 * LDA], Wc1[32 * LDW], Wc2[32 * LDW];
  const long rowbase = (long)blockIdx.x * 64;
  const int tid = threadIdx.x;
  const int rowp = tid >> 3, colg = tid & 7;
  const int col0 = colg * 16;

  f32x4 acc1[2][4], acc2[2][4];
#pragma unroll
  for (int i = 0; i < 2; ++i)
#pragma unroll
    for (int j = 0; j < 4; ++j) {
      acc1[i][j] = f32x4{0.f, 0.f, 0.f, 0.f};
      acc2[i][j] = f32x4{0.f, 0.f, 0.f, 0.f};
    }

  for (int kc = 0; kc < 256; kc += 32) {
    stageA_f32(A1, Qf, rowbase, 256, kc, tid);
    stageA_f32(A2, Qhf, rowbase, 256, kc, tid);
    stageW(Wc1, W1, kc, 128, 0, tid);
    stageW(Wc2, W2, kc, 128, 0, tid);
    __syncthreads();
    for (int kk = 0; kk < 32; ++kk) {
      float a10 = A1[(2 * rowp) * LDA + kk], a11 = A1[(2 * rowp + 1) * LDA + kk];
      float a20 = A2[(2 * rowp) * LDA + kk], a21 = A2[(2 * rowp + 1) * LDA + kk];
      const float* w1r = Wc1 + kk * LDW + col0;
      const float* w2r = Wc2 + kk * LDW + col0;
#pragma unroll
      for (int j = 0; j < 4; ++j) {
        f32x4 w1v = *reinterpret_cast<const f32x4*>(w1r + j * 4);
        f32x4 w2v = *reinterpret_cast<const f32x4*>(w2r + j * 4);
        acc1[0][j] += a10 * w1v;  acc1[1][j] += a11 * w1v;
        acc2[0][j] += a20 * w2v;  acc2[1][j] += a21 * w2v;
      }
    }
    __syncthreads();
  }

  float u[2][16];
#pragma unroll
  for (int j = 0; j < 4; ++j) {
    f32x4 bb1 = *reinterpret_cast<const f32x4*>(b1 + col0 + j * 4);
    f32x4 bb2 = *reinterpret_cast<const f32x4*>(b2 + col0 + j * 4);
#pragma unroll
    for (int i = 0; i < 2; ++i)
#pragma unroll
      for (int c = 0; c < 4; ++c) {
        float v = fmaxf(acc1[i][j][c] + bb1[c], 0.f) + fmaxf(acc2[i][j][c] + bb2[c], 0.f);
        u[i][j * 4 + c] = fmaxf(v, 0.f);
      }
  }
#pragma unroll
  for (int i = 0; i < 2; ++i) {
    float s = 0.f, ss = 0.f;
#pragma unroll
    for (int c = 0; c < 16; ++c) { s += u[i][c]; ss += u[i][c] * u[i][c]; }
    s += __shfl_xor(s, 1); ss += __shfl_xor(ss, 1);
    s += __shfl_xor(s, 2); ss += __shfl_xor(ss, 2);
    s += __shfl_xor(s, 4); ss += __shfl_xor(ss, 4);
    float mean = s * (1.f / 128.f);
    float var = ss * (1.f / 128.f) - mean * mean;
    float rs = rsqrtf(fmaxf(var, 0.f) + EPS_LN);
    long row = rowbase + 2 * rowp + i;
#pragma unroll
    for (int j = 0; j < 4; ++j) {
      f32x4 gg = *reinterpret_cast<const f32x4*>(ggam + col0 + j * 4);
      f32x4 gb = *reinterpret_cast<const f32x4*>(gbet + col0 + j * 4);
      f32x4 o;
#pragma unroll
      for (int c = 0; c < 4; ++c)
        o[c] = (u[i][j * 4 + c] - mean) * rs * gg[c] + gb[c];
      *reinterpret_cast<f32x4*>(G + (size_t)row * 128 + col0 + j * 4) = o;
    }
  }
}

// ---- gate E + product (in place): G *= LN(relu(Qh W3+b3)), fp32 ----
__global__ __launch_bounds__(256) void gateE_f32_kernel(
    const float* __restrict__ Qhf, const float* __restrict__ W3,
    const float* __restrict__ b3, const float* __restrict__ egam,
    const float* __restrict__ ebet, float* G) {
  __shared__ float A1[64 * LDA], Wc1[32 * LDW];
  const long rowbase = (long)blockIdx.x * 64;
  const int tid = threadIdx.x;
  const int rowp = tid >> 3, colg = tid & 7;
  const int col0 = colg * 16;

  f32x4 acc[2][4];
#pragma unroll
  for (int i = 0; i < 2; ++i)
#pragma unroll
    for (int j = 0; j < 4; ++j) acc[i][j] = f32x4{0.f, 0.f, 0.f, 0.f};

  for (int kc = 0; kc < 256; kc += 32) {
    stageA_f32(A1, Qhf, rowbase, 256, kc, tid);
    stageW(Wc1, W3, kc, 128, 0, tid);
    __syncthreads();
    for (int kk = 0; kk < 32; ++kk) {
      float a0 = A1[(2 * rowp) * LDA + kk], a1 = A1[(2 * rowp + 1) * LDA + kk];
      const float* wr = Wc1 + kk * LDW + col0;
#pragma unroll
      for (int j = 0; j < 4; ++j) {
        f32x4 wv = *reinterpret_cast<const f32x4*>(wr + j * 4);
        acc[0][j] += a0 * wv;  acc[1][j] += a1 * wv;
      }
    }
    __syncthreads();
  }

  float u[2][16];
#pragma unroll
  for (int j = 0; j < 4; ++j) {
    f32x4 bb = *reinterpret_cast<const f32x4*>(b3 + col0 + j * 4);
#pragma unroll
    for (int i = 0; i < 2; ++i)
#pragma unroll
      for (int c = 0; c < 4; ++c)
        u[i][j * 4 + c] = fmaxf(acc[i][j][c] + bb[c], 0.f);
  }
#pragma unroll
  for (int i = 0; i < 2; ++i) {
    float s = 0.f, ss = 0.f;
#pragma unroll
    for (int c = 0; c < 16; ++c) { s += u[i][c]; ss += u[i][c] * u[i][c]; }
    s += __shfl_xor(s, 1); ss += __shfl_xor(ss, 1);
    s += __shfl_xor(s, 2); ss += __shfl_xor(ss, 2);
    s += __shfl_xor(s, 4); ss += __shfl_xor(ss, 4);
    float mean = s * (1.f / 128.f);
    float var = ss * (1.f / 128.f) - mean * mean;
    float rs = rsqrtf(fmaxf(var, 0.f) + EPS_LN);
    long row = rowbase + 2 * rowp + i;
#pragma unroll
    for (int j = 0; j < 4; ++j) {
      f32x4 eg = *reinterpret_cast<const f32x4*>(egam + col0 + j * 4);
      f32x4 eb = *reinterpret_cast<const f32x4*>(ebet + col0 + j * 4);
      f32x4 gv = *reinterpret_cast<f32x4*>(G + (size_t)row * 128 + col0 + j * 4);
      f32x4 o;
#pragma unroll
      for (int c = 0; c < 4; ++c) {
        float e = (u[i][j * 4 + c] - mean) * rs * eg[c] + eb[c];
        o[c] = gv[c] * e;
      }
      *reinterpret_cast<f32x4*>(G + (size_t)row * 128 + col0 + j * 4) = o;  // GE in place
    }
  }
}

// ---- out0 = relu(Q Wf + bf) + relu(GE Wc + bc), fp32 ----
__global__ __launch_bounds__(256) void outc_f32_kernel(
    const float* __restrict__ Qf, const float* __restrict__ GE,
    const float* __restrict__ Wf, const float* __restrict__ Wcw,
    const float* __restrict__ bf_, const float* __restrict__ bc_,
    float* __restrict__ out0) {
  __shared__ float A1[64 * LDA], Wc1[32 * LDW];
  const long rowbase = (long)blockIdx.x * 64;
  const int tid = threadIdx.x;
  const int rowp = tid >> 3, colg = tid & 7;
  const int col0 = colg * 16;

  f32x4 acc4[2][4], acc5[2][4];
#pragma unroll
  for (int i = 0; i < 2; ++i)
#pragma unroll
    for (int j = 0; j < 4; ++j) {
      acc4[i][j] = f32x4{0.f, 0.f, 0.f, 0.f};
      acc5[i][j] = f32x4{0.f, 0.f, 0.f, 0.f};
    }

  for (int kc = 0; kc < 256; kc += 32) {
    stageA_f32(A1, Qf, rowbase, 256, kc, tid);
    stageW(Wc1, Wf, kc, 128, 0, tid);
    __syncthreads();
    for (int kk = 0; kk < 32; ++kk) {
      float a0 = A1[(2 * rowp) * LDA + kk], a1 = A1[(2 * rowp + 1) * LDA + kk];
      const float* wr = Wc1 + kk * LDW + col0;
#pragma unroll
      for (int j = 0; j < 4; ++j) {
        f32x4 wv = *reinterpret_cast<const f32x4*>(wr + j * 4);
        acc4[0][j] += a0 * wv;  acc4[1][j] += a1 * wv;
      }
    }
    __syncthreads();
  }
  for (int kc = 0; kc < 128; kc += 32) {
    stageA_f32(A1, GE, rowbase, 128, kc, tid);
    stageW(Wc1, Wcw, kc, 128, 0, tid);
    __syncthreads();
    for (int kk = 0; kk < 32; ++kk) {
      float a0 = A1[(2 * rowp) * LDA + kk], a1 = A1[(2 * rowp + 1) * LDA + kk];
      const float* wr = Wc1 + kk * LDW + col0;
#pragma unroll
      for (int j = 0; j < 4; ++j) {
        f32x4 wv = *reinterpret_cast<const f32x4*>(wr + j * 4);
        acc5[0][j] += a0 * wv;  acc5[1][j] += a1 * wv;
      }
    }
    __syncthreads();
  }

#pragma unroll
  for (int i = 0; i < 2; ++i) {
    long row = rowbase + 2 * rowp + i;
#pragma unroll
    for (int j = 0; j < 4; ++j) {
      f32x4 fb = *reinterpret_cast<const f32x4*>(bf_ + col0 + j * 4);
      f32x4 cb = *reinterpret_cast<const f32x4*>(bc_ + col0 + j * 4);
      f32x4 o;
#pragma unroll
      for (int c = 0; c < 4; ++c)
        o[c] = fmaxf(acc4[i][j][c] + fb[c], 0.f) + fmaxf(acc5[i][j][c] + cb[c], 0.f);
      *reinterpret_cast<f32x4*>(out0 + (size_t)row * 128 + col0 + j * 4) = o;
    }
  }
}

// ------------------------------- host launcher -------------------------------------
extern "C" void kernel_launch(void* const* d_in, const int* in_sizes, int n_in,
                              void* d_out, int out_size, void* d_ws, size_t ws_size,
                              hipStream_t stream) {
  const float* x1 = (const float*)d_in[0];
  const float* x2 = (const float*)d_in[1];
  const float* W_q = (const float*)d_in[2];  const float* b_q = (const float*)d_in[3];
  const float* W_k = (const float*)d_in[4];  const float* b_k = (const float*)d_in[5];
  const float* W_v = (const float*)d_in[6];  const float* b_v = (const float*)d_in[7];
  const float* W1  = (const float*)d_in[8];  const float* b1  = (const float*)d_in[9];
  const float* W2  = (const float*)d_in[10]; const float* b2  = (const float*)d_in[11];
  const float* W3  = (const float*)d_in[12]; const float* b3  = (const float*)d_in[13];
  const float* ggam = (const float*)d_in[14]; const float* gbet = (const float*)d_in[15];
  const float* egam = (const float*)d_in[16]; const float* ebet = (const float*)d_in[17];
  const float* W_c = (const float*)d_in[18]; const float* b_c = (const float*)d_in[19];
  const float* W_f = (const float*)d_in[20]; const float* b_f = (const float*)d_in[21];

  float* out0 = (float*)d_out;
  float* Smat = out0 + (size_t)MROWS * NOUT;  // attn region, also scratch for raw scores

  // workspace layout (bytes); peak live = 63.0 MB
  char* ws = (char*)d_ws;
  float*          Qf   = (float*)(ws + 0);               // 16 MB f32, [qkv..outc]
  unsigned short* tQh  = (unsigned short*)(ws + 16777216); // 8 MB [qkv..score]
  unsigned short* Khi  = (unsigned short*)(ws + 25165824); // 8 MB [qkv..score]
  unsigned short* tKh  = (unsigned short*)(ws + 33554432); // 8 MB [qkv..score]
  unsigned short* VtHi = (unsigned short*)(ws + 41943040); // 8 MB [qkv..pv]
  unsigned short* VtLo = (unsigned short*)(ws + 50331648); // 8 MB [qkv..pv]
  float*          part = (float*)(ws + 58720256);          // 4 MB [score..merge]
  float*          mrow = (float*)(ws + 62914560);          // 64 KB
  float*          linv = (float*)(ws + 62980096);          // 64 KB
  // overlays (regions dead after score):
  float*          Qhf  = (float*)(ws + 16777216);          // 16 MB f32 over tQh+Khi [pv..outc]
  float*          Gm   = (float*)(ws + 33554432);          // 8 MB f32 over tKh [gateG..outc]

  qkv_f32_kernel<<<dim3(256, 2, 3), 256, 0, stream>>>(
      x1, x2, W_q, W_k, W_v, b_q, b_k, b_v, Qf, tQh, Khi, tKh, VtHi, VtLo);
  score_kernel<<<dim3(32, 32, 4), 512, 0, stream>>>(Qf, tQh, Khi, tKh, Smat, part);
  merge_kernel<<<64, 256, 0, stream>>>(part, mrow, linv);
  zero_kernel<<<4096, 256, 0, stream>>>(Qhf, MROWS * 256 / 4);  // Qhf overlays tQh/Khi (dead after score)
  pv_kernel<<<dim3(64, 4, PV_SPLIT), 256, 0, stream>>>(Smat, mrow, linv, VtHi, VtLo, Qhf);
  gateG_f32_kernel<<<256, 256, 0, stream>>>(Qf, Qhf, W1, W2, b1, b2, ggam, gbet, Gm);
  gateE_f32_kernel<<<256, 256, 0, stream>>>(Qhf, W3, b3, egam, ebet, Gm);
  outc_f32_kernel<<<256, 256, 0, stream>>>(Qf, Gm, W_f, W_c, b_f, b_c, out0);
}